// Round 8
// baseline (247.995 us; speedup 1.0000x reference)
//
#include <hip/hip_runtime.h>
#include <math.h>

#define N_NODES 50000
#define N_EDGES 800000
#define D_IN    256
#define D_HID   128
#define D_OUT   64

// bucketed CSR build: bucket = dst >> 8 (256 nodes/bucket)
#define NB 196
#define CH 2048     // edges per scatter1 block -> 391 blocks
#define SLAB 4608   // per-bucket slab capacity (mean 4096 + 8 sigma)

typedef unsigned int u32;
typedef unsigned short u16;
typedef __attribute__((ext_vector_type(8))) short bf16x8;   // 8 bf16 = 4 VGPRs
typedef __attribute__((ext_vector_type(4))) float f32x4;

__device__ __forceinline__ float bflo(u32 u) {
    union { u32 i; float f; } c; c.i = u << 16; return c.f;
}
__device__ __forceinline__ float bfhi(u32 u) {
    union { u32 i; float f; } c; c.i = u & 0xffff0000u; return c.f;
}
__device__ __forceinline__ u32 pack_bf2(float a, float b) {
    union { float f; u32 i; } ca, cb; ca.f = a; cb.f = b;
    u32 ra = (ca.i + 0x7fffu + ((ca.i >> 16) & 1u)) >> 16;
    u32 rb = (cb.i + 0x7fffu + ((cb.i >> 16) & 1u)) & 0xffff0000u;
    return ra | rb;
}

__device__ __forceinline__ int edge_at(const void* ei, int is64, int which, int i) {
    if (is64) return (int)((const long long*)ei)[(size_t)which * N_EDGES + i];
    return ((const int*)ei)[which * N_EDGES + i];
}

// per-block edge dtype detection: odd 32-bit words of the first 256 entries are
// all zero iff layout is int64 (values < 2^31).
__device__ __forceinline__ int detect_is64(const void* ei, int t, int* s_is32) {
    if (t == 0) *s_is32 = 0;
    __syncthreads();
    if (t < 256) {
        int vv = ((const int*)ei)[2 * t + 1];
        if (vv != 0) atomicOr(s_is32, 1);
    }
    __syncthreads();
    return (*s_is32 == 0);
}

// ---------------- bucketed CSR build (2 passes, slab-allocated) ----------------

__global__ __launch_bounds__(256) void k_scatter1(const void* __restrict__ ei,
                                                  int* __restrict__ bcur,
                                                  u32* __restrict__ ebuf) {
    __shared__ int h[NB], gbase[NB], lc[NB];
    __shared__ int s_is32;
    int t = threadIdx.x;
    int is64 = detect_is64(ei, t, &s_is32);
    for (int i = t; i < NB; i += 256) { h[i] = 0; lc[i] = 0; }
    __syncthreads();
    int base = blockIdx.x * CH;

    u32 p[CH / 256];
    #pragma unroll
    for (int j = 0; j < CH / 256; ++j) {
        int i = base + j * 256 + t;
        if (i < N_EDGES) {
            int s = edge_at(ei, is64, 0, i);
            int d = edge_at(ei, is64, 1, i);
            p[j] = (u32)s | ((u32)d << 16);
            atomicAdd(&h[d >> 8], 1);
        }
    }
    __syncthreads();
    for (int i = t; i < NB; i += 256) if (h[i]) gbase[i] = atomicAdd(&bcur[i], h[i]);
    __syncthreads();
    #pragma unroll
    for (int j = 0; j < CH / 256; ++j) {
        int i = base + j * 256 + t;
        if (i < N_EDGES) {
            int b = (int)(p[j] >> 24);               // dst >> 8
            int lp = atomicAdd(&lc[b], 1);
            ebuf[gbase[b] + lp] = p[j];              // block-private contiguous run: L2-local
        }
    }
}

__global__ __launch_bounds__(256) void k_scatter2(const u32* __restrict__ ebuf,
                                                  const int* __restrict__ bcur,
                                                  int* __restrict__ rowstart,
                                                  int* __restrict__ cnt,
                                                  float* __restrict__ dinv,
                                                  int* __restrict__ colidx) {
    __shared__ int h2[256], lofs[256], cur[256], sm[256];
    int b = blockIdx.x, t = threadIdx.x;
    int e0 = b * SLAB, ne = bcur[b] - e0;
    h2[t] = 0; cur[t] = 0;
    __syncthreads();
    for (int i = t; i < ne; i += 256) {
        u32 p = ebuf[e0 + i];
        atomicAdd(&h2[(p >> 16) & 255], 1);
    }
    __syncthreads();
    int v = h2[t]; sm[t] = v; __syncthreads();
    for (int off = 1; off < 256; off <<= 1) {
        int a = (t >= off) ? sm[t - off] : 0;
        __syncthreads();
        sm[t] += a;
        __syncthreads();
    }
    lofs[t] = sm[t] - v;
    __syncthreads();
    int node = (b << 8) + t;
    if (node < N_NODES) {
        rowstart[node] = e0 + lofs[t];
        cnt[node] = v;
        dinv[node] = rsqrtf(1.0f + (float)v);
    }
    for (int i = t; i < ne; i += 256) {
        u32 p = ebuf[e0 + i];
        int dl = (p >> 16) & 255;
        int lp = atomicAdd(&cur[dl], 1);
        colidx[e0 + lofs[dl] + lp] = (int)(p & 0xffffu);
    }
}

// ------ W pre-split: W1 trunc hi/lo bf16 [c][k]; W2 transposed f32 [f][k] ------
// also initializes bcur to slab bases.
__global__ void k_wsplit(const float* __restrict__ W1, u16* __restrict__ t1h,
                         u16* __restrict__ t1l, const float* __restrict__ W2,
                         float* __restrict__ w2tg, int* __restrict__ bcur) {
    int i = blockIdx.x * 256 + threadIdx.x;
    if (i < NB) bcur[i] = i * SLAB;
    if (i < D_IN * D_HID) {
        int k = i / D_HID, c = i - k * D_HID;
        u32 bits = __float_as_uint(W1[i]);
        u32 hb = bits & 0xffff0000u;
        float lo = __uint_as_float(bits) - __uint_as_float(hb);
        t1h[(size_t)c * D_IN + k] = (u16)(hb >> 16);
        t1l[(size_t)c * D_IN + k] = (u16)(__float_as_uint(lo) >> 16);
    }
    int j = i - D_IN * D_HID;
    if (j >= 0 && j < D_HID * D_OUT) {
        int k = j / D_OUT, f = j - k * D_OUT;
        w2tg[f * D_HID + k] = W2[j];
    }
}

// ---- MFMA GEMM (A = f32): Cp[r,:] = pack_bf16( (A[r,:]@W) * dinv[r] ) ----
// BM=128, 4 waves x (2x16 rows, NF cols). K-step 32. Trunc hi/lo split, 3-term MFMA.
template <int K, int NF>
__global__ __launch_bounds__(256) void k_gemm_mfma(
    const float* __restrict__ A, const u16* __restrict__ tHi,
    const u16* __restrict__ tLo, const float* __restrict__ dinv,
    u32* __restrict__ Cp, int M) {
    constexpr int NT = NF / 16;
    constexpr int LDK = 40;
    __shared__ u16 aH[128][LDK], aL[128][LDK];
    __shared__ u16 wH[NF][LDK], wL[NF][LDK];

    const int t = threadIdx.x;
    const int lane = t & 63, wv = t >> 6;
    const int m0 = blockIdx.x * 128;
    const int lr = lane & 15, lk = (lane >> 4) * 8;

    f32x4 acc[2][NT] = {};

    const int arow = t >> 1;
    const int akq = (t & 1) * 16;
    const bool aok = (m0 + arow) < M;
    const float* asrc = A + (size_t)(m0 + arow) * K + akq;

    for (int ks = 0; ks < K; ks += 32) {
        {
            float f[16];
            #pragma unroll
            for (int j = 0; j < 16; ++j) f[j] = 0.0f;
            if (aok) {
                const float4* p = (const float4*)(asrc + ks);
                float4 v0 = p[0], v1 = p[1], v2 = p[2], v3 = p[3];
                f[0] = v0.x; f[1] = v0.y; f[2]  = v0.z; f[3]  = v0.w;
                f[4] = v1.x; f[5] = v1.y; f[6]  = v1.z; f[7]  = v1.w;
                f[8] = v2.x; f[9] = v2.y; f[10] = v2.z; f[11] = v2.w;
                f[12] = v3.x; f[13] = v3.y; f[14] = v3.z; f[15] = v3.w;
            }
            u32 hp[8], lp[8];
            #pragma unroll
            for (int q = 0; q < 8; ++q) {
                u32 b0 = __float_as_uint(f[2 * q]);
                u32 b1 = __float_as_uint(f[2 * q + 1]);
                u32 h0 = b0 & 0xffff0000u, h1 = b1 & 0xffff0000u;
                float l0 = f[2 * q] - __uint_as_float(h0);
                float l1 = f[2 * q + 1] - __uint_as_float(h1);
                hp[q] = (h0 >> 16) | h1;
                lp[q] = (__float_as_uint(l0) >> 16) | (__float_as_uint(l1) & 0xffff0000u);
            }
            *(uint4*)&aH[arow][akq + 0] = make_uint4(hp[0], hp[1], hp[2], hp[3]);
            *(uint4*)&aH[arow][akq + 8] = make_uint4(hp[4], hp[5], hp[6], hp[7]);
            *(uint4*)&aL[arow][akq + 0] = make_uint4(lp[0], lp[1], lp[2], lp[3]);
            *(uint4*)&aL[arow][akq + 8] = make_uint4(lp[4], lp[5], lp[6], lp[7]);
        }
        #pragma unroll
        for (int idx = t; idx < NF * 4; idx += 256) {
            int col = idx >> 2;
            int k8 = (idx & 3) * 8;
            *(uint4*)&wH[col][k8] = *(const uint4*)&tHi[(size_t)col * K + ks + k8];
            *(uint4*)&wL[col][k8] = *(const uint4*)&tLo[(size_t)col * K + ks + k8];
        }
        __syncthreads();

        bf16x8 afH[2], afL[2];
        #pragma unroll
        for (int mt = 0; mt < 2; ++mt) {
            int r = wv * 32 + mt * 16 + lr;
            afH[mt] = *(const bf16x8*)&aH[r][lk];
            afL[mt] = *(const bf16x8*)&aL[r][lk];
        }
        #pragma unroll
        for (int nt = 0; nt < NT; ++nt) {
            bf16x8 bh = *(const bf16x8*)&wH[nt * 16 + lr][lk];
            bf16x8 bl = *(const bf16x8*)&wL[nt * 16 + lr][lk];
            #pragma unroll
            for (int mt = 0; mt < 2; ++mt) {
                acc[mt][nt] = __builtin_amdgcn_mfma_f32_16x16x32_bf16(afH[mt], bh, acc[mt][nt], 0, 0, 0);
                acc[mt][nt] = __builtin_amdgcn_mfma_f32_16x16x32_bf16(afL[mt], bh, acc[mt][nt], 0, 0, 0);
                acc[mt][nt] = __builtin_amdgcn_mfma_f32_16x16x32_bf16(afH[mt], bl, acc[mt][nt], 0, 0, 0);
            }
        }
        __syncthreads();
    }

    #pragma unroll
    for (int mt = 0; mt < 2; ++mt) {
        #pragma unroll
        for (int r = 0; r < 4; ++r) {
            int row = m0 + wv * 32 + mt * 16 + (lane >> 4) * 4 + r;
            float dv = (row < M) ? dinv[row] : 0.0f;
            #pragma unroll
            for (int nt = 0; nt < NT; ++nt) {
                float v = acc[mt][nt][r] * dv;
                float vn = __shfl_xor(v, 1);
                if (!(lane & 1) && row < M) {
                    Cp[(size_t)row * (NF / 2) + nt * 8 + (lr >> 1)] = pack_bf2(v, vn);
                }
            }
        }
    }
}

// ------- fused layer-1 aggregate + gate + layer-2 GEMV (gemm2 eliminated) -------
// 512 threads = 8 waves, one node per wave (grid 6250 x 8 = 50000 exactly).
// Gather phase identical to the proven round-3 agg1. Then: gated h -> LDS,
// per-lane f32 gemv against LDS-staged W2T (stride 130 rows: b64 reads, <=4-way
// bank aliasing on an otherwise-idle LDS pipe). Output = h2s (packed bf16,
// pre-scaled by dinv) consumed by k_agg2 unchanged.
// LDS: 64x130x4 (W2T) + 8x128x4 (h) = 36.5 KB -> 4 blocks/CU = 32 waves/CU.
__global__ __launch_bounds__(512) void k_agg1g(
        const u32* __restrict__ hs, const int* __restrict__ rowstart,
        const int* __restrict__ cnt, const int* __restrict__ colidx,
        const float* __restrict__ dinv,
        const float* __restrict__ b, const float* __restrict__ aw,
        const float* __restrict__ ab, const float* __restrict__ w2tg,
        u32* __restrict__ h2s) {
    __shared__ float w2t[64 * 130];
    __shared__ float hbuf[8][128];
    int t = threadIdx.x;
    for (int i = t; i < 64 * 128; i += 512) {
        int f = i >> 7, k = i & 127;
        w2t[f * 130 + k] = w2tg[i];
    }
    __syncthreads();

    int wv = t >> 6, l = t & 63;
    int v = blockIdx.x * 8 + wv;          // grid exact: v < 50000 always
    float dv = dinv[v];
    u32 su = hs[(size_t)v * 64 + l];
    float ax = bflo(su), ay = bfhi(su);
    int start = rowstart[v], len = cnt[v];
    const int* cx = colidx + start;
    int j = 0;
    for (; j + 8 <= len; j += 8) {
        int s0 = cx[j], s1 = cx[j + 1], s2 = cx[j + 2], s3 = cx[j + 3];
        int s4 = cx[j + 4], s5 = cx[j + 5], s6 = cx[j + 6], s7 = cx[j + 7];
        u32 u0 = hs[(size_t)s0 * 64 + l];
        u32 u1 = hs[(size_t)s1 * 64 + l];
        u32 u2 = hs[(size_t)s2 * 64 + l];
        u32 u3 = hs[(size_t)s3 * 64 + l];
        u32 u4 = hs[(size_t)s4 * 64 + l];
        u32 u5 = hs[(size_t)s5 * 64 + l];
        u32 u6 = hs[(size_t)s6 * 64 + l];
        u32 u7 = hs[(size_t)s7 * 64 + l];
        ax += bflo(u0) + bflo(u1) + bflo(u2) + bflo(u3)
            + bflo(u4) + bflo(u5) + bflo(u6) + bflo(u7);
        ay += bfhi(u0) + bfhi(u1) + bfhi(u2) + bfhi(u3)
            + bfhi(u4) + bfhi(u5) + bfhi(u6) + bfhi(u7);
    }
    for (; j + 4 <= len; j += 4) {
        int s0 = cx[j], s1 = cx[j + 1], s2 = cx[j + 2], s3 = cx[j + 3];
        u32 u0 = hs[(size_t)s0 * 64 + l];
        u32 u1 = hs[(size_t)s1 * 64 + l];
        u32 u2 = hs[(size_t)s2 * 64 + l];
        u32 u3 = hs[(size_t)s3 * 64 + l];
        ax += bflo(u0) + bflo(u1) + bflo(u2) + bflo(u3);
        ay += bfhi(u0) + bfhi(u1) + bfhi(u2) + bfhi(u3);
    }
    for (; j < len; ++j) {
        u32 u = hs[(size_t)cx[j] * 64 + l];
        ax += bflo(u); ay += bfhi(u);
    }
    float2 bp = ((const float2*)b)[l];
    ax = fmaxf(ax * dv + bp.x, 0.0f);
    ay = fmaxf(ay * dv + bp.y, 0.0f);
    float2 ap = ((const float2*)aw)[l];
    float p = ax * ap.x + ay * ap.y;
    for (int off = 32; off; off >>= 1) p += __shfl_xor(p, off);
    float g = 1.0f / (1.0f + expf(-(p + ab[0])));

    // gated h -> LDS (wave-private row; same-wave read-after-write, no barrier)
    *(float2*)&hbuf[wv][2 * l] = make_float2(ax * g, ay * g);

    // gemv: lane l computes out[l] = sum_k h[k] * W2T[l][k], exact f32
    float o0 = 0.0f, o1 = 0.0f;
    const float* wrow = &w2t[l * 130];
    #pragma unroll 8
    for (int k2 = 0; k2 < 64; k2 += 2) {
        float2 h0 = *(const float2*)&hbuf[wv][2 * k2];       // uniform -> broadcast
        float2 h1 = *(const float2*)&hbuf[wv][2 * k2 + 2];
        float2 w0 = *(const float2*)&wrow[2 * k2];
        float2 w1 = *(const float2*)&wrow[2 * k2 + 2];
        o0 += h0.x * w0.x + h0.y * w0.y;
        o1 += h1.x * w1.x + h1.y * w1.y;
    }
    float o = (o0 + o1) * dv;
    float on = __shfl_xor(o, 1);
    if (!(l & 1)) h2s[(size_t)v * 32 + (l >> 1)] = pack_bf2(o, on);
}

// ---------------- layer-2 aggregate + bias + sigmoid gate (unchanged) ----------------
__global__ __launch_bounds__(256) void k_agg2(
        const u32* __restrict__ hs, const int* __restrict__ rowstart,
        const int* __restrict__ cnt, const int* __restrict__ colidx,
        const float* __restrict__ dinv,
        const float* __restrict__ b, const float* __restrict__ aw,
        const float* __restrict__ ab, float* __restrict__ out) {
    int v = blockIdx.x * 4 + (threadIdx.x >> 6);
    int l = threadIdx.x & 63;
    if (v >= N_NODES) return;
    int c = l & 31, half = l >> 5;
    float dv = dinv[v];
    float ax = 0.0f, ay = 0.0f;
    if (half == 0) {
        u32 su = hs[(size_t)v * 32 + c];
        ax = bflo(su); ay = bfhi(su);
    }
    int start = rowstart[v], len = cnt[v];
    const int* cx = colidx + start;
    int j = half;
    for (; j + 6 < len; j += 8) {
        int s0 = cx[j], s1 = cx[j + 2], s2 = cx[j + 4], s3 = cx[j + 6];
        u32 u0 = hs[(size_t)s0 * 32 + c];
        u32 u1 = hs[(size_t)s1 * 32 + c];
        u32 u2 = hs[(size_t)s2 * 32 + c];
        u32 u3 = hs[(size_t)s3 * 32 + c];
        ax += bflo(u0) + bflo(u1) + bflo(u2) + bflo(u3);
        ay += bfhi(u0) + bfhi(u1) + bfhi(u2) + bfhi(u3);
    }
    for (; j + 2 < len; j += 4) {
        int s0 = cx[j], s1 = cx[j + 2];
        u32 u0 = hs[(size_t)s0 * 32 + c];
        u32 u1 = hs[(size_t)s1 * 32 + c];
        ax += bflo(u0) + bflo(u1);
        ay += bfhi(u0) + bfhi(u1);
    }
    if (j < len) {
        u32 u = hs[(size_t)cx[j] * 32 + c];
        ax += bflo(u); ay += bfhi(u);
    }
    ax += __shfl_xor(ax, 32);
    ay += __shfl_xor(ay, 32);
    float2 bp = ((const float2*)b)[c];
    ax = ax * dv + bp.x;
    ay = ay * dv + bp.y;
    float2 ap = ((const float2*)aw)[c];
    float p = ax * ap.x + ay * ap.y;
    for (int off = 16; off; off >>= 1) p += __shfl_xor(p, off);
    float g = 1.0f / (1.0f + expf(-(p + ab[0])));
    if (half == 0) ((float2*)out)[(size_t)v * 32 + c] = make_float2(ax * g, ay * g);
}

// ---------------- launch ----------------

static inline size_t align_up(size_t x, size_t a) { return (x + a - 1) & ~(a - 1); }

extern "C" void kernel_launch(void* const* d_in, const int* in_sizes, int n_in,
                              void* d_out, int out_size, void* d_ws, size_t ws_size,
                              hipStream_t stream) {
    const float* x   = (const float*)d_in[0];
    const void*  ei  = d_in[1];
    const float* W1  = (const float*)d_in[2];
    const float* b1  = (const float*)d_in[3];
    const float* W2  = (const float*)d_in[4];
    const float* b2  = (const float*)d_in[5];
    const float* aw1 = (const float*)d_in[6];
    const float* ab1 = (const float*)d_in[7];
    const float* aw2 = (const float*)d_in[8];
    const float* ab2 = (const float*)d_in[9];
    float* out = (float*)d_out;

    char* w = (char*)d_ws;
    size_t off = 0;
    int*   bcur     = (int*)(w + off); off = align_up(off + NB * 4, 256);
    int*   cnt      = (int*)(w + off); off = align_up(off + N_NODES * 4, 256);
    int*   rowstart = (int*)(w + off); off = align_up(off + N_NODES * 4, 256);
    float* dinv     = (float*)(w + off); off = align_up(off + N_NODES * 4, 256);
    u32*   ebuf     = (u32*)(w + off); off = align_up(off + (size_t)NB * SLAB * 4, 256);
    int*   colidx   = (int*)(w + off); off = align_up(off + (size_t)NB * SLAB * 4, 256);
    u32*   h1s      = (u32*)(w + off); off = align_up(off + (size_t)N_NODES * 64 * 4, 256);
    u32*   h2s      = (u32*)(w + off); off = align_up(off + (size_t)N_NODES * 32 * 4, 256);
    u16*   wt1h     = (u16*)(w + off); off = align_up(off + (size_t)D_IN * D_HID * 2, 256);
    u16*   wt1l     = (u16*)(w + off); off = align_up(off + (size_t)D_IN * D_HID * 2, 256);
    float* w2tg     = (float*)(w + off); off = align_up(off + (size_t)D_OUT * D_HID * 4, 256);
    (void)ws_size; (void)out_size; (void)n_in; (void)in_sizes;

    // wsplit also initializes bcur to slab bases
    k_wsplit<<<(D_IN * D_HID + D_HID * D_OUT + 255) / 256, 256, 0, stream>>>(
        W1, wt1h, wt1l, W2, w2tg, bcur);

    k_scatter1<<<(N_EDGES + CH - 1) / CH, 256, 0, stream>>>(ei, bcur, ebuf);
    k_scatter2<<<NB, 256, 0, stream>>>(ebuf, bcur, rowstart, cnt, dinv, colidx);

    // layer 1: h1s = pack_bf16((x @ W1) * dinv), split-bf16 MFMA
    k_gemm_mfma<D_IN, D_HID><<<(N_NODES + 127) / 128, 256, 0, stream>>>(
        x, wt1h, wt1l, dinv, h1s, N_NODES);

    // fused: layer-1 aggregate+gate, then layer-2 GEMV -> h2s (gemm2 eliminated)
    k_agg1g<<<N_NODES / 8, 512, 0, stream>>>(
        h1s, rowstart, cnt, colidx, dinv, b1, aw1, ab1, w2tg, h2s);

    // layer 2 aggregate + gate -> out
    k_agg2<<<(N_NODES + 3) / 4, 256, 0, stream>>>(
        h2s, rowstart, cnt, colidx, dinv, b2, aw2, ab2, out);
}

// Round 9
// 223.501 us; speedup vs baseline: 1.1096x; 1.1096x over previous
//
#include <hip/hip_runtime.h>
#include <math.h>

#define N_NODES 50000
#define N_EDGES 800000
#define D_IN    256
#define D_HID   128
#define D_OUT   64

// bucketed CSR build: bucket = dst >> 8 (256 nodes/bucket)
#define NB 196
#define CH 2048     // edges per scatter1 block -> 391 blocks
#define SLAB 4608   // per-bucket slab capacity (mean 4096 + 8 sigma)

typedef unsigned int u32;
typedef unsigned short u16;
typedef __attribute__((ext_vector_type(8))) short bf16x8;   // 8 bf16 = 4 VGPRs
typedef __attribute__((ext_vector_type(4))) float f32x4;

__device__ __forceinline__ float bflo(u32 u) {
    union { u32 i; float f; } c; c.i = u << 16; return c.f;
}
__device__ __forceinline__ float bfhi(u32 u) {
    union { u32 i; float f; } c; c.i = u & 0xffff0000u; return c.f;
}
__device__ __forceinline__ u32 pack_bf2(float a, float b) {
    union { float f; u32 i; } ca, cb; ca.f = a; cb.f = b;
    u32 ra = (ca.i + 0x7fffu + ((ca.i >> 16) & 1u)) >> 16;
    u32 rb = (cb.i + 0x7fffu + ((cb.i >> 16) & 1u)) & 0xffff0000u;
    return ra | rb;
}

__device__ __forceinline__ int edge_at(const void* ei, int is64, int which, int i) {
    if (is64) return (int)((const long long*)ei)[(size_t)which * N_EDGES + i];
    return ((const int*)ei)[which * N_EDGES + i];
}

// per-block edge dtype detection: odd 32-bit words of the first 256 entries are
// all zero iff layout is int64 (values < 2^31).
__device__ __forceinline__ int detect_is64(const void* ei, int t, int* s_is32) {
    if (t == 0) *s_is32 = 0;
    __syncthreads();
    if (t < 256) {
        int vv = ((const int*)ei)[2 * t + 1];
        if (vv != 0) atomicOr(s_is32, 1);
    }
    __syncthreads();
    return (*s_is32 == 0);
}

// ---------------- bucketed CSR build (2 passes, slab-allocated) ----------------

__global__ __launch_bounds__(256) void k_scatter1(const void* __restrict__ ei,
                                                  int* __restrict__ bcur,
                                                  u32* __restrict__ ebuf) {
    __shared__ int h[NB], gbase[NB], lc[NB];
    __shared__ int s_is32;
    int t = threadIdx.x;
    int is64 = detect_is64(ei, t, &s_is32);
    for (int i = t; i < NB; i += 256) { h[i] = 0; lc[i] = 0; }
    __syncthreads();
    int base = blockIdx.x * CH;

    u32 p[CH / 256];
    #pragma unroll
    for (int j = 0; j < CH / 256; ++j) {
        int i = base + j * 256 + t;
        if (i < N_EDGES) {
            int s = edge_at(ei, is64, 0, i);
            int d = edge_at(ei, is64, 1, i);
            p[j] = (u32)s | ((u32)d << 16);
            atomicAdd(&h[d >> 8], 1);
        }
    }
    __syncthreads();
    for (int i = t; i < NB; i += 256) if (h[i]) gbase[i] = atomicAdd(&bcur[i], h[i]);
    __syncthreads();
    #pragma unroll
    for (int j = 0; j < CH / 256; ++j) {
        int i = base + j * 256 + t;
        if (i < N_EDGES) {
            int b = (int)(p[j] >> 24);               // dst >> 8
            int lp = atomicAdd(&lc[b], 1);
            ebuf[gbase[b] + lp] = p[j];              // block-private contiguous run: L2-local
        }
    }
}

__global__ __launch_bounds__(256) void k_scatter2(const u32* __restrict__ ebuf,
                                                  const int* __restrict__ bcur,
                                                  int* __restrict__ rowstart,
                                                  int* __restrict__ cnt,
                                                  float* __restrict__ dinv,
                                                  int* __restrict__ colidx) {
    __shared__ int h2[256], lofs[256], cur[256], sm[256];
    int b = blockIdx.x, t = threadIdx.x;
    int e0 = b * SLAB, ne = bcur[b] - e0;
    h2[t] = 0; cur[t] = 0;
    __syncthreads();
    for (int i = t; i < ne; i += 256) {
        u32 p = ebuf[e0 + i];
        atomicAdd(&h2[(p >> 16) & 255], 1);
    }
    __syncthreads();
    int v = h2[t]; sm[t] = v; __syncthreads();
    for (int off = 1; off < 256; off <<= 1) {
        int a = (t >= off) ? sm[t - off] : 0;
        __syncthreads();
        sm[t] += a;
        __syncthreads();
    }
    lofs[t] = sm[t] - v;
    __syncthreads();
    int node = (b << 8) + t;
    if (node < N_NODES) {
        rowstart[node] = e0 + lofs[t];
        cnt[node] = v;
        dinv[node] = rsqrtf(1.0f + (float)v);
    }
    for (int i = t; i < ne; i += 256) {
        u32 p = ebuf[e0 + i];
        int dl = (p >> 16) & 255;
        int lp = atomicAdd(&cur[dl], 1);
        colidx[e0 + lofs[dl] + lp] = (int)(p & 0xffffu);
    }
}

// ------ W pre-split (both layers, truncation split: hi+lo == w exactly in f32) ------
// also initializes bcur to slab bases.
__global__ void k_wsplit(const float* __restrict__ W1, u16* __restrict__ t1h,
                         u16* __restrict__ t1l, const float* __restrict__ W2,
                         u16* __restrict__ t2h, u16* __restrict__ t2l,
                         int* __restrict__ bcur) {
    int i = blockIdx.x * 256 + threadIdx.x;
    if (i < NB) bcur[i] = i * SLAB;
    if (i < D_IN * D_HID) {
        int k = i / D_HID, c = i - k * D_HID;
        u32 bits = __float_as_uint(W1[i]);
        u32 hb = bits & 0xffff0000u;
        float lo = __uint_as_float(bits) - __uint_as_float(hb);
        t1h[(size_t)c * D_IN + k] = (u16)(hb >> 16);
        t1l[(size_t)c * D_IN + k] = (u16)(__float_as_uint(lo) >> 16);
    }
    int j = i - D_IN * D_HID;
    if (j >= 0 && j < D_HID * D_OUT) {
        int k = j / D_OUT, c = j - k * D_OUT;
        u32 bits = __float_as_uint(W2[j]);
        u32 hb = bits & 0xffff0000u;
        float lo = __uint_as_float(bits) - __uint_as_float(hb);
        t2h[(size_t)c * D_HID + k] = (u16)(hb >> 16);
        t2l[(size_t)c * D_HID + k] = (u16)(__float_as_uint(lo) >> 16);
    }
}

// ---- MFMA GEMM (A = f32): Cp[r,:] = pack_bf16( (A[r,:]@W) * dinv[r] ) ----
// BM=128, 4 waves x (2x16 rows, NF cols). K-step 32. Trunc hi/lo split, 3-term MFMA.
template <int K, int NF>
__global__ __launch_bounds__(256) void k_gemm_mfma(
    const float* __restrict__ A, const u16* __restrict__ tHi,
    const u16* __restrict__ tLo, const float* __restrict__ dinv,
    u32* __restrict__ Cp, int M) {
    constexpr int NT = NF / 16;
    constexpr int LDK = 40;
    __shared__ u16 aH[128][LDK], aL[128][LDK];
    __shared__ u16 wH[NF][LDK], wL[NF][LDK];

    const int t = threadIdx.x;
    const int lane = t & 63, wv = t >> 6;
    const int m0 = blockIdx.x * 128;
    const int lr = lane & 15, lk = (lane >> 4) * 8;

    f32x4 acc[2][NT] = {};

    const int arow = t >> 1;
    const int akq = (t & 1) * 16;
    const bool aok = (m0 + arow) < M;
    const float* asrc = A + (size_t)(m0 + arow) * K + akq;

    for (int ks = 0; ks < K; ks += 32) {
        {
            float f[16];
            #pragma unroll
            for (int j = 0; j < 16; ++j) f[j] = 0.0f;
            if (aok) {
                const float4* p = (const float4*)(asrc + ks);
                float4 v0 = p[0], v1 = p[1], v2 = p[2], v3 = p[3];
                f[0] = v0.x; f[1] = v0.y; f[2]  = v0.z; f[3]  = v0.w;
                f[4] = v1.x; f[5] = v1.y; f[6]  = v1.z; f[7]  = v1.w;
                f[8] = v2.x; f[9] = v2.y; f[10] = v2.z; f[11] = v2.w;
                f[12] = v3.x; f[13] = v3.y; f[14] = v3.z; f[15] = v3.w;
            }
            u32 hp[8], lp[8];
            #pragma unroll
            for (int q = 0; q < 8; ++q) {
                u32 b0 = __float_as_uint(f[2 * q]);
                u32 b1 = __float_as_uint(f[2 * q + 1]);
                u32 h0 = b0 & 0xffff0000u, h1 = b1 & 0xffff0000u;
                float l0 = f[2 * q] - __uint_as_float(h0);
                float l1 = f[2 * q + 1] - __uint_as_float(h1);
                hp[q] = (h0 >> 16) | h1;
                lp[q] = (__float_as_uint(l0) >> 16) | (__float_as_uint(l1) & 0xffff0000u);
            }
            *(uint4*)&aH[arow][akq + 0] = make_uint4(hp[0], hp[1], hp[2], hp[3]);
            *(uint4*)&aH[arow][akq + 8] = make_uint4(hp[4], hp[5], hp[6], hp[7]);
            *(uint4*)&aL[arow][akq + 0] = make_uint4(lp[0], lp[1], lp[2], lp[3]);
            *(uint4*)&aL[arow][akq + 8] = make_uint4(lp[4], lp[5], lp[6], lp[7]);
        }
        #pragma unroll
        for (int idx = t; idx < NF * 4; idx += 256) {
            int col = idx >> 2;
            int k8 = (idx & 3) * 8;
            *(uint4*)&wH[col][k8] = *(const uint4*)&tHi[(size_t)col * K + ks + k8];
            *(uint4*)&wL[col][k8] = *(const uint4*)&tLo[(size_t)col * K + ks + k8];
        }
        __syncthreads();

        bf16x8 afH[2], afL[2];
        #pragma unroll
        for (int mt = 0; mt < 2; ++mt) {
            int r = wv * 32 + mt * 16 + lr;
            afH[mt] = *(const bf16x8*)&aH[r][lk];
            afL[mt] = *(const bf16x8*)&aL[r][lk];
        }
        #pragma unroll
        for (int nt = 0; nt < NT; ++nt) {
            bf16x8 bh = *(const bf16x8*)&wH[nt * 16 + lr][lk];
            bf16x8 bl = *(const bf16x8*)&wL[nt * 16 + lr][lk];
            #pragma unroll
            for (int mt = 0; mt < 2; ++mt) {
                acc[mt][nt] = __builtin_amdgcn_mfma_f32_16x16x32_bf16(afH[mt], bh, acc[mt][nt], 0, 0, 0);
                acc[mt][nt] = __builtin_amdgcn_mfma_f32_16x16x32_bf16(afL[mt], bh, acc[mt][nt], 0, 0, 0);
                acc[mt][nt] = __builtin_amdgcn_mfma_f32_16x16x32_bf16(afH[mt], bl, acc[mt][nt], 0, 0, 0);
            }
        }
        __syncthreads();
    }

    #pragma unroll
    for (int mt = 0; mt < 2; ++mt) {
        #pragma unroll
        for (int r = 0; r < 4; ++r) {
            int row = m0 + wv * 32 + mt * 16 + (lane >> 4) * 4 + r;
            float dv = (row < M) ? dinv[row] : 0.0f;
            #pragma unroll
            for (int nt = 0; nt < NT; ++nt) {
                float v = acc[mt][nt][r] * dv;
                float vn = __shfl_xor(v, 1);
                if (!(lane & 1) && row < M) {
                    Cp[(size_t)row * (NF / 2) + nt * 8 + (lr >> 1)] = pack_bf2(v, vn);
                }
            }
        }
    }
}

// ---------------- fused aggregate + bias (+relu) + sigmoid gate ----------------
// 256-thread blocks, 4 nodes/block (one per wave); 12 neighbor rows in flight
// (latency-bound gather, VGPR ~50 keeps max occupancy band).

__global__ __launch_bounds__(256) void k_agg1(
        const u32* __restrict__ hs, const int* __restrict__ rowstart,
        const int* __restrict__ cnt, const int* __restrict__ colidx,
        const float* __restrict__ dinv,
        const float* __restrict__ b, const float* __restrict__ aw,
        const float* __restrict__ ab, float* __restrict__ out) {
    int v = blockIdx.x * 4 + (threadIdx.x >> 6);
    int l = threadIdx.x & 63;
    if (v >= N_NODES) return;
    float dv = dinv[v];
    u32 su = hs[(size_t)v * 64 + l];
    float ax = bflo(su), ay = bfhi(su);
    int start = rowstart[v], len = cnt[v];
    const int* cx = colidx + start;
    int j = 0;
    for (; j + 12 <= len; j += 12) {
        int s0 = cx[j], s1 = cx[j + 1], s2 = cx[j + 2], s3 = cx[j + 3];
        int s4 = cx[j + 4], s5 = cx[j + 5], s6 = cx[j + 6], s7 = cx[j + 7];
        int s8 = cx[j + 8], s9 = cx[j + 9], s10 = cx[j + 10], s11 = cx[j + 11];
        u32 u0 = hs[(size_t)s0 * 64 + l];
        u32 u1 = hs[(size_t)s1 * 64 + l];
        u32 u2 = hs[(size_t)s2 * 64 + l];
        u32 u3 = hs[(size_t)s3 * 64 + l];
        u32 u4 = hs[(size_t)s4 * 64 + l];
        u32 u5 = hs[(size_t)s5 * 64 + l];
        u32 u6 = hs[(size_t)s6 * 64 + l];
        u32 u7 = hs[(size_t)s7 * 64 + l];
        u32 u8 = hs[(size_t)s8 * 64 + l];
        u32 u9 = hs[(size_t)s9 * 64 + l];
        u32 u10 = hs[(size_t)s10 * 64 + l];
        u32 u11 = hs[(size_t)s11 * 64 + l];
        ax += bflo(u0) + bflo(u1) + bflo(u2) + bflo(u3)
            + bflo(u4) + bflo(u5) + bflo(u6) + bflo(u7)
            + bflo(u8) + bflo(u9) + bflo(u10) + bflo(u11);
        ay += bfhi(u0) + bfhi(u1) + bfhi(u2) + bfhi(u3)
            + bfhi(u4) + bfhi(u5) + bfhi(u6) + bfhi(u7)
            + bfhi(u8) + bfhi(u9) + bfhi(u10) + bfhi(u11);
    }
    for (; j + 4 <= len; j += 4) {
        int s0 = cx[j], s1 = cx[j + 1], s2 = cx[j + 2], s3 = cx[j + 3];
        u32 u0 = hs[(size_t)s0 * 64 + l];
        u32 u1 = hs[(size_t)s1 * 64 + l];
        u32 u2 = hs[(size_t)s2 * 64 + l];
        u32 u3 = hs[(size_t)s3 * 64 + l];
        ax += bflo(u0) + bflo(u1) + bflo(u2) + bflo(u3);
        ay += bfhi(u0) + bfhi(u1) + bfhi(u2) + bfhi(u3);
    }
    for (; j < len; ++j) {
        u32 u = hs[(size_t)cx[j] * 64 + l];
        ax += bflo(u); ay += bfhi(u);
    }
    float2 bp = ((const float2*)b)[l];
    ax = fmaxf(ax * dv + bp.x, 0.0f);
    ay = fmaxf(ay * dv + bp.y, 0.0f);
    float2 ap = ((const float2*)aw)[l];
    float p = ax * ap.x + ay * ap.y;
    for (int off = 32; off; off >>= 1) p += __shfl_xor(p, off);
    float g = 1.0f / (1.0f + expf(-(p + ab[0])));
    ((float2*)out)[(size_t)v * 64 + l] = make_float2(ax * g, ay * g);
}

// layer 2: wave split into 2 half-waves on alternating neighbors, 6 rows in
// flight per half (12/wave).
__global__ __launch_bounds__(256) void k_agg2(
        const u32* __restrict__ hs, const int* __restrict__ rowstart,
        const int* __restrict__ cnt, const int* __restrict__ colidx,
        const float* __restrict__ dinv,
        const float* __restrict__ b, const float* __restrict__ aw,
        const float* __restrict__ ab, float* __restrict__ out) {
    int v = blockIdx.x * 4 + (threadIdx.x >> 6);
    int l = threadIdx.x & 63;
    if (v >= N_NODES) return;
    int c = l & 31, half = l >> 5;
    float dv = dinv[v];
    float ax = 0.0f, ay = 0.0f;
    if (half == 0) {
        u32 su = hs[(size_t)v * 32 + c];
        ax = bflo(su); ay = bfhi(su);
    }
    int start = rowstart[v], len = cnt[v];
    const int* cx = colidx + start;
    int j = half;
    for (; j + 10 < len; j += 12) {
        int s0 = cx[j], s1 = cx[j + 2], s2 = cx[j + 4];
        int s3 = cx[j + 6], s4 = cx[j + 8], s5 = cx[j + 10];
        u32 u0 = hs[(size_t)s0 * 32 + c];
        u32 u1 = hs[(size_t)s1 * 32 + c];
        u32 u2 = hs[(size_t)s2 * 32 + c];
        u32 u3 = hs[(size_t)s3 * 32 + c];
        u32 u4 = hs[(size_t)s4 * 32 + c];
        u32 u5 = hs[(size_t)s5 * 32 + c];
        ax += bflo(u0) + bflo(u1) + bflo(u2) + bflo(u3) + bflo(u4) + bflo(u5);
        ay += bfhi(u0) + bfhi(u1) + bfhi(u2) + bfhi(u3) + bfhi(u4) + bfhi(u5);
    }
    for (; j + 2 < len; j += 4) {
        int s0 = cx[j], s1 = cx[j + 2];
        u32 u0 = hs[(size_t)s0 * 32 + c];
        u32 u1 = hs[(size_t)s1 * 32 + c];
        ax += bflo(u0) + bflo(u1);
        ay += bfhi(u0) + bfhi(u1);
    }
    if (j < len) {
        u32 u = hs[(size_t)cx[j] * 32 + c];
        ax += bflo(u); ay += bfhi(u);
    }
    ax += __shfl_xor(ax, 32);
    ay += __shfl_xor(ay, 32);
    float2 bp = ((const float2*)b)[c];
    ax = ax * dv + bp.x;
    ay = ay * dv + bp.y;
    float2 ap = ((const float2*)aw)[c];
    float p = ax * ap.x + ay * ap.y;
    for (int off = 16; off; off >>= 1) p += __shfl_xor(p, off);
    float g = 1.0f / (1.0f + expf(-(p + ab[0])));
    if (half == 0) ((float2*)out)[(size_t)v * 32 + c] = make_float2(ax * g, ay * g);
}

// ---------------- launch ----------------

static inline size_t align_up(size_t x, size_t a) { return (x + a - 1) & ~(a - 1); }

extern "C" void kernel_launch(void* const* d_in, const int* in_sizes, int n_in,
                              void* d_out, int out_size, void* d_ws, size_t ws_size,
                              hipStream_t stream) {
    const float* x   = (const float*)d_in[0];
    const void*  ei  = d_in[1];
    const float* W1  = (const float*)d_in[2];
    const float* b1  = (const float*)d_in[3];
    const float* W2  = (const float*)d_in[4];
    const float* b2  = (const float*)d_in[5];
    const float* aw1 = (const float*)d_in[6];
    const float* ab1 = (const float*)d_in[7];
    const float* aw2 = (const float*)d_in[8];
    const float* ab2 = (const float*)d_in[9];
    float* out = (float*)d_out;

    char* w = (char*)d_ws;
    size_t off = 0;
    int*   bcur     = (int*)(w + off); off = align_up(off + NB * 4, 256);
    int*   cnt      = (int*)(w + off); off = align_up(off + N_NODES * 4, 256);
    int*   rowstart = (int*)(w + off); off = align_up(off + N_NODES * 4, 256);
    float* dinv     = (float*)(w + off); off = align_up(off + N_NODES * 4, 256);
    u32*   ebuf     = (u32*)(w + off); off = align_up(off + (size_t)NB * SLAB * 4, 256);
    int*   colidx   = (int*)(w + off); off = align_up(off + (size_t)NB * SLAB * 4, 256);
    u32*   h1s      = (u32*)(w + off); off = align_up(off + (size_t)N_NODES * 64 * 4, 256);
    float* h1g      = (float*)(w + off); off = align_up(off + (size_t)N_NODES * D_HID * 4, 256);
    u32*   h2s      = (u32*)(w + off); off = align_up(off + (size_t)N_NODES * 32 * 4, 256);
    u16*   wt1h     = (u16*)(w + off); off = align_up(off + (size_t)D_IN * D_HID * 2, 256);
    u16*   wt1l     = (u16*)(w + off); off = align_up(off + (size_t)D_IN * D_HID * 2, 256);
    u16*   wt2h     = (u16*)(w + off); off = align_up(off + (size_t)D_HID * D_OUT * 2, 256);
    u16*   wt2l     = (u16*)(w + off); off = align_up(off + (size_t)D_HID * D_OUT * 2, 256);
    (void)ws_size; (void)out_size; (void)n_in; (void)in_sizes;

    // wsplit also initializes bcur to slab bases (no memset / histogram dispatch)
    k_wsplit<<<(D_IN * D_HID + D_HID * D_OUT + 255) / 256, 256, 0, stream>>>(
        W1, wt1h, wt1l, W2, wt2h, wt2l, bcur);

    k_scatter1<<<(N_EDGES + CH - 1) / CH, 256, 0, stream>>>(ei, bcur, ebuf);
    k_scatter2<<<NB, 256, 0, stream>>>(ebuf, bcur, rowstart, cnt, dinv, colidx);

    // layer 1: h1s = pack_bf16((x @ W1) * dinv), split-bf16 MFMA
    k_gemm_mfma<D_IN, D_HID><<<(N_NODES + 127) / 128, 256, 0, stream>>>(
        x, wt1h, wt1l, dinv, h1s, N_NODES);
    k_agg1<<<(N_NODES + 3) / 4, 256, 0, stream>>>(
        h1s, rowstart, cnt, colidx, dinv, b1, aw1, ab1, h1g);

    // layer 2: h2s = pack_bf16((h1g @ W2) * dinv), split-bf16 MFMA
    k_gemm_mfma<D_HID, D_OUT><<<(N_NODES + 127) / 128, 256, 0, stream>>>(
        h1g, wt2h, wt2l, dinv, h2s, N_NODES);
    k_agg2<<<(N_NODES + 3) / 4, 256, 0, stream>>>(
        h2s, rowstart, cnt, colidx, dinv, b2, aw2, ab2, out);
}

// Round 11
// 222.230 us; speedup vs baseline: 1.1159x; 1.0057x over previous
//
#include <hip/hip_runtime.h>
#include <math.h>

#define N_NODES 50000
#define N_EDGES 800000
#define D_IN    256
#define D_HID   128
#define D_OUT   64

// bucketed CSR build: bucket = dst >> 8 (256 nodes/bucket)
#define NB 196
#define CH 2048     // edges per scatter1 block -> 391 blocks
#define SLAB 4608   // per-bucket slab capacity (mean 4096 + 8 sigma)

typedef unsigned int u32;
typedef unsigned short u16;
typedef __attribute__((ext_vector_type(8))) short bf16x8;   // 8 bf16 = 4 VGPRs
typedef __attribute__((ext_vector_type(4))) float f32x4;
typedef __attribute__((ext_vector_type(2))) float f32x2;    // -> v_pk_add_f32

__device__ __forceinline__ float bflo(u32 u) {
    union { u32 i; float f; } c; c.i = u << 16; return c.f;
}
__device__ __forceinline__ float bfhi(u32 u) {
    union { u32 i; float f; } c; c.i = u & 0xffff0000u; return c.f;
}
// unpack u32 (2 packed bf16) -> float2; accumulate with ONE v_pk_add_f32
__device__ __forceinline__ f32x2 up2(u32 u) {
    f32x2 r; r.x = bflo(u); r.y = bfhi(u); return r;
}
__device__ __forceinline__ u32 pack_bf2(float a, float b) {
    union { float f; u32 i; } ca, cb; ca.f = a; cb.f = b;
    u32 ra = (ca.i + 0x7fffu + ((ca.i >> 16) & 1u)) >> 16;
    u32 rb = (cb.i + 0x7fffu + ((cb.i >> 16) & 1u)) & 0xffff0000u;
    return ra | rb;
}

__device__ __forceinline__ int edge_at(const void* ei, int is64, int which, int i) {
    if (is64) return (int)((const long long*)ei)[(size_t)which * N_EDGES + i];
    return ((const int*)ei)[which * N_EDGES + i];
}

// per-block edge dtype detection: odd 32-bit words of the first 256 entries are
// all zero iff layout is int64 (values < 2^31).
__device__ __forceinline__ int detect_is64(const void* ei, int t, int* s_is32) {
    if (t == 0) *s_is32 = 0;
    __syncthreads();
    if (t < 256) {
        int vv = ((const int*)ei)[2 * t + 1];
        if (vv != 0) atomicOr(s_is32, 1);
    }
    __syncthreads();
    return (*s_is32 == 0);
}

// ---------------- bucketed CSR build (2 passes, slab-allocated) ----------------

__global__ __launch_bounds__(256) void k_scatter1(const void* __restrict__ ei,
                                                  int* __restrict__ bcur,
                                                  u32* __restrict__ ebuf) {
    __shared__ int h[NB], gbase[NB], lc[NB];
    __shared__ int s_is32;
    int t = threadIdx.x;
    int is64 = detect_is64(ei, t, &s_is32);
    for (int i = t; i < NB; i += 256) { h[i] = 0; lc[i] = 0; }
    __syncthreads();
    int base = blockIdx.x * CH;

    u32 p[CH / 256];
    #pragma unroll
    for (int j = 0; j < CH / 256; ++j) {
        int i = base + j * 256 + t;
        if (i < N_EDGES) {
            int s = edge_at(ei, is64, 0, i);
            int d = edge_at(ei, is64, 1, i);
            p[j] = (u32)s | ((u32)d << 16);
            atomicAdd(&h[d >> 8], 1);
        }
    }
    __syncthreads();
    for (int i = t; i < NB; i += 256) if (h[i]) gbase[i] = atomicAdd(&bcur[i], h[i]);
    __syncthreads();
    #pragma unroll
    for (int j = 0; j < CH / 256; ++j) {
        int i = base + j * 256 + t;
        if (i < N_EDGES) {
            int b = (int)(p[j] >> 24);               // dst >> 8
            int lp = atomicAdd(&lc[b], 1);
            ebuf[gbase[b] + lp] = p[j];              // block-private contiguous run: L2-local
        }
    }
}

__global__ __launch_bounds__(256) void k_scatter2(const u32* __restrict__ ebuf,
                                                  const int* __restrict__ bcur,
                                                  int* __restrict__ rowstart,
                                                  int* __restrict__ cnt,
                                                  float* __restrict__ dinv,
                                                  int* __restrict__ colidx) {
    __shared__ int h2[256], lofs[256], cur[256], sm[256];
    int b = blockIdx.x, t = threadIdx.x;
    int e0 = b * SLAB, ne = bcur[b] - e0;
    h2[t] = 0; cur[t] = 0;
    __syncthreads();
    for (int i = t; i < ne; i += 256) {
        u32 p = ebuf[e0 + i];
        atomicAdd(&h2[(p >> 16) & 255], 1);
    }
    __syncthreads();
    int v = h2[t]; sm[t] = v; __syncthreads();
    for (int off = 1; off < 256; off <<= 1) {
        int a = (t >= off) ? sm[t - off] : 0;
        __syncthreads();
        sm[t] += a;
        __syncthreads();
    }
    lofs[t] = sm[t] - v;
    __syncthreads();
    int node = (b << 8) + t;
    if (node < N_NODES) {
        rowstart[node] = e0 + lofs[t];
        cnt[node] = v;
        dinv[node] = rsqrtf(1.0f + (float)v);
    }
    for (int i = t; i < ne; i += 256) {
        u32 p = ebuf[e0 + i];
        int dl = (p >> 16) & 255;
        int lp = atomicAdd(&cur[dl], 1);
        colidx[e0 + lofs[dl] + lp] = (int)(p & 0xffffu);
    }
}

// ------ W pre-split (both layers, truncation split: hi+lo == w exactly in f32) ------
// also initializes bcur to slab bases.
__global__ void k_wsplit(const float* __restrict__ W1, u16* __restrict__ t1h,
                         u16* __restrict__ t1l, const float* __restrict__ W2,
                         u16* __restrict__ t2h, u16* __restrict__ t2l,
                         int* __restrict__ bcur) {
    int i = blockIdx.x * 256 + threadIdx.x;
    if (i < NB) bcur[i] = i * SLAB;
    if (i < D_IN * D_HID) {
        int k = i / D_HID, c = i - k * D_HID;
        u32 bits = __float_as_uint(W1[i]);
        u32 hb = bits & 0xffff0000u;
        float lo = __uint_as_float(bits) - __uint_as_float(hb);
        t1h[(size_t)c * D_IN + k] = (u16)(hb >> 16);
        t1l[(size_t)c * D_IN + k] = (u16)(__float_as_uint(lo) >> 16);
    }
    int j = i - D_IN * D_HID;
    if (j >= 0 && j < D_HID * D_OUT) {
        int k = j / D_OUT, c = j - k * D_OUT;
        u32 bits = __float_as_uint(W2[j]);
        u32 hb = bits & 0xffff0000u;
        float lo = __uint_as_float(bits) - __uint_as_float(hb);
        t2h[(size_t)c * D_HID + k] = (u16)(hb >> 16);
        t2l[(size_t)c * D_HID + k] = (u16)(__float_as_uint(lo) >> 16);
    }
}

// ---- MFMA GEMM (A = f32): Cp[r,:] = pack_bf16( (A[r,:]@W) * dinv[r] ) ----
// BM=128, 4 waves x (2x16 rows, NF cols). K-step 32. Trunc hi/lo split, 3-term MFMA.
template <int K, int NF>
__global__ __launch_bounds__(256) void k_gemm_mfma(
    const float* __restrict__ A, const u16* __restrict__ tHi,
    const u16* __restrict__ tLo, const float* __restrict__ dinv,
    u32* __restrict__ Cp, int M) {
    constexpr int NT = NF / 16;
    constexpr int LDK = 40;
    __shared__ u16 aH[128][LDK], aL[128][LDK];
    __shared__ u16 wH[NF][LDK], wL[NF][LDK];

    const int t = threadIdx.x;
    const int lane = t & 63, wv = t >> 6;
    const int m0 = blockIdx.x * 128;
    const int lr = lane & 15, lk = (lane >> 4) * 8;

    f32x4 acc[2][NT] = {};

    const int arow = t >> 1;
    const int akq = (t & 1) * 16;
    const bool aok = (m0 + arow) < M;
    const float* asrc = A + (size_t)(m0 + arow) * K + akq;

    for (int ks = 0; ks < K; ks += 32) {
        {
            float f[16];
            #pragma unroll
            for (int j = 0; j < 16; ++j) f[j] = 0.0f;
            if (aok) {
                const float4* p = (const float4*)(asrc + ks);
                float4 v0 = p[0], v1 = p[1], v2 = p[2], v3 = p[3];
                f[0] = v0.x; f[1] = v0.y; f[2]  = v0.z; f[3]  = v0.w;
                f[4] = v1.x; f[5] = v1.y; f[6]  = v1.z; f[7]  = v1.w;
                f[8] = v2.x; f[9] = v2.y; f[10] = v2.z; f[11] = v2.w;
                f[12] = v3.x; f[13] = v3.y; f[14] = v3.z; f[15] = v3.w;
            }
            u32 hp[8], lp[8];
            #pragma unroll
            for (int q = 0; q < 8; ++q) {
                u32 b0 = __float_as_uint(f[2 * q]);
                u32 b1 = __float_as_uint(f[2 * q + 1]);
                u32 h0 = b0 & 0xffff0000u, h1 = b1 & 0xffff0000u;
                float l0 = f[2 * q] - __uint_as_float(h0);
                float l1 = f[2 * q + 1] - __uint_as_float(h1);
                hp[q] = (h0 >> 16) | h1;
                lp[q] = (__float_as_uint(l0) >> 16) | (__float_as_uint(l1) & 0xffff0000u);
            }
            *(uint4*)&aH[arow][akq + 0] = make_uint4(hp[0], hp[1], hp[2], hp[3]);
            *(uint4*)&aH[arow][akq + 8] = make_uint4(hp[4], hp[5], hp[6], hp[7]);
            *(uint4*)&aL[arow][akq + 0] = make_uint4(lp[0], lp[1], lp[2], lp[3]);
            *(uint4*)&aL[arow][akq + 8] = make_uint4(lp[4], lp[5], lp[6], lp[7]);
        }
        #pragma unroll
        for (int idx = t; idx < NF * 4; idx += 256) {
            int col = idx >> 2;
            int k8 = (idx & 3) * 8;
            *(uint4*)&wH[col][k8] = *(const uint4*)&tHi[(size_t)col * K + ks + k8];
            *(uint4*)&wL[col][k8] = *(const uint4*)&tLo[(size_t)col * K + ks + k8];
        }
        __syncthreads();

        bf16x8 afH[2], afL[2];
        #pragma unroll
        for (int mt = 0; mt < 2; ++mt) {
            int r = wv * 32 + mt * 16 + lr;
            afH[mt] = *(const bf16x8*)&aH[r][lk];
            afL[mt] = *(const bf16x8*)&aL[r][lk];
        }
        #pragma unroll
        for (int nt = 0; nt < NT; ++nt) {
            bf16x8 bh = *(const bf16x8*)&wH[nt * 16 + lr][lk];
            bf16x8 bl = *(const bf16x8*)&wL[nt * 16 + lr][lk];
            #pragma unroll
            for (int mt = 0; mt < 2; ++mt) {
                acc[mt][nt] = __builtin_amdgcn_mfma_f32_16x16x32_bf16(afH[mt], bh, acc[mt][nt], 0, 0, 0);
                acc[mt][nt] = __builtin_amdgcn_mfma_f32_16x16x32_bf16(afL[mt], bh, acc[mt][nt], 0, 0, 0);
                acc[mt][nt] = __builtin_amdgcn_mfma_f32_16x16x32_bf16(afH[mt], bl, acc[mt][nt], 0, 0, 0);
            }
        }
        __syncthreads();
    }

    #pragma unroll
    for (int mt = 0; mt < 2; ++mt) {
        #pragma unroll
        for (int r = 0; r < 4; ++r) {
            int row = m0 + wv * 32 + mt * 16 + (lane >> 4) * 4 + r;
            float dv = (row < M) ? dinv[row] : 0.0f;
            #pragma unroll
            for (int nt = 0; nt < NT; ++nt) {
                float v = acc[mt][nt][r] * dv;
                float vn = __shfl_xor(v, 1);
                if (!(lane & 1) && row < M) {
                    Cp[(size_t)row * (NF / 2) + nt * 8 + (lr >> 1)] = pack_bf2(v, vn);
                }
            }
        }
    }
}

// ---------------- fused aggregate + bias (+relu) + sigmoid gate ----------------
// 256-thread blocks, 4 nodes/block (one per wave); 12 neighbor rows in flight.
// Accumulation in float2 ext-vectors -> v_pk_add_f32 (2 adds / instruction):
// per loaded u32 the VALU cost is lshl + and + 1 pk_add (was lshl+and+2 adds).

__global__ __launch_bounds__(256) void k_agg1(
        const u32* __restrict__ hs, const int* __restrict__ rowstart,
        const int* __restrict__ cnt, const int* __restrict__ colidx,
        const float* __restrict__ dinv,
        const float* __restrict__ b, const float* __restrict__ aw,
        const float* __restrict__ ab, float* __restrict__ out) {
    int v = blockIdx.x * 4 + (threadIdx.x >> 6);
    int l = threadIdx.x & 63;
    if (v >= N_NODES) return;
    float dv = dinv[v];
    f32x2 A0 = up2(hs[(size_t)v * 64 + l]);   // self
    f32x2 A1 = {0.0f, 0.0f}, A2 = {0.0f, 0.0f}, A3 = {0.0f, 0.0f};
    int start = rowstart[v], len = cnt[v];
    const int* cx = colidx + start;
    int j = 0;
    for (; j + 12 <= len; j += 12) {
        int s0 = cx[j], s1 = cx[j + 1], s2 = cx[j + 2], s3 = cx[j + 3];
        int s4 = cx[j + 4], s5 = cx[j + 5], s6 = cx[j + 6], s7 = cx[j + 7];
        int s8 = cx[j + 8], s9 = cx[j + 9], s10 = cx[j + 10], s11 = cx[j + 11];
        u32 u0 = hs[(size_t)s0 * 64 + l];
        u32 u1 = hs[(size_t)s1 * 64 + l];
        u32 u2 = hs[(size_t)s2 * 64 + l];
        u32 u3 = hs[(size_t)s3 * 64 + l];
        u32 u4 = hs[(size_t)s4 * 64 + l];
        u32 u5 = hs[(size_t)s5 * 64 + l];
        u32 u6 = hs[(size_t)s6 * 64 + l];
        u32 u7 = hs[(size_t)s7 * 64 + l];
        u32 u8 = hs[(size_t)s8 * 64 + l];
        u32 u9 = hs[(size_t)s9 * 64 + l];
        u32 u10 = hs[(size_t)s10 * 64 + l];
        u32 u11 = hs[(size_t)s11 * 64 + l];
        A0 += up2(u0); A1 += up2(u1); A2 += up2(u2); A3 += up2(u3);
        A0 += up2(u4); A1 += up2(u5); A2 += up2(u6); A3 += up2(u7);
        A0 += up2(u8); A1 += up2(u9); A2 += up2(u10); A3 += up2(u11);
    }
    for (; j + 4 <= len; j += 4) {
        int s0 = cx[j], s1 = cx[j + 1], s2 = cx[j + 2], s3 = cx[j + 3];
        u32 u0 = hs[(size_t)s0 * 64 + l];
        u32 u1 = hs[(size_t)s1 * 64 + l];
        u32 u2 = hs[(size_t)s2 * 64 + l];
        u32 u3 = hs[(size_t)s3 * 64 + l];
        A0 += up2(u0); A1 += up2(u1); A2 += up2(u2); A3 += up2(u3);
    }
    for (; j < len; ++j) {
        A0 += up2(hs[(size_t)cx[j] * 64 + l]);
    }
    f32x2 T = (A0 + A1) + (A2 + A3);
    float ax = T.x, ay = T.y;
    float2 bp = ((const float2*)b)[l];
    ax = fmaxf(ax * dv + bp.x, 0.0f);
    ay = fmaxf(ay * dv + bp.y, 0.0f);
    float2 ap = ((const float2*)aw)[l];
    float p = ax * ap.x + ay * ap.y;
    for (int off = 32; off; off >>= 1) p += __shfl_xor(p, off);
    float g = 1.0f / (1.0f + expf(-(p + ab[0])));
    ((float2*)out)[(size_t)v * 64 + l] = make_float2(ax * g, ay * g);
}

// layer 2: wave split into 2 half-waves on alternating neighbors, 6 rows in
// flight per half (12/wave); pk-add accumulation.
__global__ __launch_bounds__(256) void k_agg2(
        const u32* __restrict__ hs, const int* __restrict__ rowstart,
        const int* __restrict__ cnt, const int* __restrict__ colidx,
        const float* __restrict__ dinv,
        const float* __restrict__ b, const float* __restrict__ aw,
        const float* __restrict__ ab, float* __restrict__ out) {
    int v = blockIdx.x * 4 + (threadIdx.x >> 6);
    int l = threadIdx.x & 63;
    if (v >= N_NODES) return;
    int c = l & 31, half = l >> 5;
    float dv = dinv[v];
    f32x2 A0 = {0.0f, 0.0f}, A1 = {0.0f, 0.0f};
    if (half == 0) A0 = up2(hs[(size_t)v * 32 + c]);   // self
    int start = rowstart[v], len = cnt[v];
    const int* cx = colidx + start;
    int j = half;
    for (; j + 10 < len; j += 12) {
        int s0 = cx[j], s1 = cx[j + 2], s2 = cx[j + 4];
        int s3 = cx[j + 6], s4 = cx[j + 8], s5 = cx[j + 10];
        u32 u0 = hs[(size_t)s0 * 32 + c];
        u32 u1 = hs[(size_t)s1 * 32 + c];
        u32 u2 = hs[(size_t)s2 * 32 + c];
        u32 u3 = hs[(size_t)s3 * 32 + c];
        u32 u4 = hs[(size_t)s4 * 32 + c];
        u32 u5 = hs[(size_t)s5 * 32 + c];
        A0 += up2(u0); A1 += up2(u1);
        A0 += up2(u2); A1 += up2(u3);
        A0 += up2(u4); A1 += up2(u5);
    }
    for (; j + 2 < len; j += 4) {
        int s0 = cx[j], s1 = cx[j + 2];
        A0 += up2(hs[(size_t)s0 * 32 + c]);
        A1 += up2(hs[(size_t)s1 * 32 + c]);
    }
    if (j < len) {
        A0 += up2(hs[(size_t)cx[j] * 32 + c]);
    }
    f32x2 T = A0 + A1;
    float ax = T.x, ay = T.y;
    ax += __shfl_xor(ax, 32);
    ay += __shfl_xor(ay, 32);
    float2 bp = ((const float2*)b)[c];
    ax = ax * dv + bp.x;
    ay = ay * dv + bp.y;
    float2 ap = ((const float2*)aw)[c];
    float p = ax * ap.x + ay * ap.y;
    for (int off = 16; off; off >>= 1) p += __shfl_xor(p, off);
    float g = 1.0f / (1.0f + expf(-(p + ab[0])));
    if (half == 0) ((float2*)out)[(size_t)v * 32 + c] = make_float2(ax * g, ay * g);
}

// ---------------- launch ----------------

static inline size_t align_up(size_t x, size_t a) { return (x + a - 1) & ~(a - 1); }

extern "C" void kernel_launch(void* const* d_in, const int* in_sizes, int n_in,
                              void* d_out, int out_size, void* d_ws, size_t ws_size,
                              hipStream_t stream) {
    const float* x   = (const float*)d_in[0];
    const void*  ei  = d_in[1];
    const float* W1  = (const float*)d_in[2];
    const float* b1  = (const float*)d_in[3];
    const float* W2  = (const float*)d_in[4];
    const float* b2  = (const float*)d_in[5];
    const float* aw1 = (const float*)d_in[6];
    const float* ab1 = (const float*)d_in[7];
    const float* aw2 = (const float*)d_in[8];
    const float* ab2 = (const float*)d_in[9];
    float* out = (float*)d_out;

    char* w = (char*)d_ws;
    size_t off = 0;
    int*   bcur     = (int*)(w + off); off = align_up(off + NB * 4, 256);
    int*   cnt      = (int*)(w + off); off = align_up(off + N_NODES * 4, 256);
    int*   rowstart = (int*)(w + off); off = align_up(off + N_NODES * 4, 256);
    float* dinv     = (float*)(w + off); off = align_up(off + N_NODES * 4, 256);
    u32*   ebuf     = (u32*)(w + off); off = align_up(off + (size_t)NB * SLAB * 4, 256);
    int*   colidx   = (int*)(w + off); off = align_up(off + (size_t)NB * SLAB * 4, 256);
    u32*   h1s      = (u32*)(w + off); off = align_up(off + (size_t)N_NODES * 64 * 4, 256);
    float* h1g      = (float*)(w + off); off = align_up(off + (size_t)N_NODES * D_HID * 4, 256);
    u32*   h2s      = (u32*)(w + off); off = align_up(off + (size_t)N_NODES * 32 * 4, 256);
    u16*   wt1h     = (u16*)(w + off); off = align_up(off + (size_t)D_IN * D_HID * 2, 256);
    u16*   wt1l     = (u16*)(w + off); off = align_up(off + (size_t)D_IN * D_HID * 2, 256);
    u16*   wt2h     = (u16*)(w + off); off = align_up(off + (size_t)D_HID * D_OUT * 2, 256);
    u16*   wt2l     = (u16*)(w + off); off = align_up(off + (size_t)D_HID * D_OUT * 2, 256);
    (void)ws_size; (void)out_size; (void)n_in; (void)in_sizes;

    // wsplit also initializes bcur to slab bases (no memset / histogram dispatch)
    k_wsplit<<<(D_IN * D_HID + D_HID * D_OUT + 255) / 256, 256, 0, stream>>>(
        W1, wt1h, wt1l, W2, wt2h, wt2l, bcur);

    k_scatter1<<<(N_EDGES + CH - 1) / CH, 256, 0, stream>>>(ei, bcur, ebuf);
    k_scatter2<<<NB, 256, 0, stream>>>(ebuf, bcur, rowstart, cnt, dinv, colidx);

    // layer 1: h1s = pack_bf16((x @ W1) * dinv), split-bf16 MFMA
    k_gemm_mfma<D_IN, D_HID><<<(N_NODES + 127) / 128, 256, 0, stream>>>(
        x, wt1h, wt1l, dinv, h1s, N_NODES);
    k_agg1<<<(N_NODES + 3) / 4, 256, 0, stream>>>(
        h1s, rowstart, cnt, colidx, dinv, b1, aw1, ab1, h1g);

    // layer 2: h2s = pack_bf16((h1g @ W2) * dinv), split-bf16 MFMA
    k_gemm_mfma<D_HID, D_OUT><<<(N_NODES + 127) / 128, 256, 0, stream>>>(
        h1g, wt2h, wt2l, dinv, h2s, N_NODES);
    k_agg2<<<(N_NODES + 3) / 4, 256, 0, stream>>>(
        h2s, rowstart, cnt, colidx, dinv, b2, aw2, ab2, out);
}